// Round 5
// baseline (367.972 us; speedup 1.0000x reference)
//
#include <hip/hip_runtime.h>

// Problem constants (match reference)
constexpr int N    = 262144;   // rows
constexpr int C    = 1000;     // classes
constexpr int D    = 256;      // feature dim
constexpr int D4   = 64;       // float4s per row
constexpr int CPAD = 1024;     // padded class count (pow2 for scan/LDS)
constexpr int NB   = 64;       // histogram/scatter blocks
constexpr int ROWS_PER_B = N / NB;  // 4096
constexpr float ALPHA = 0.5f;

// Native vector type for nontemporal builtins (HIP_vector_type is rejected).
typedef float vfloat4 __attribute__((ext_vector_type(4)));

// ---------------- workspace layout (d_ws) ----------------
// int   hist  [NB][CPAD]   256 KB  (fully written by hist_kernel)
// int   counts[CPAD]         4 KB  (written by scatter block 0)
// int   S     [N]            1 MB  packed (row<<10)|label, sorted by label
// float sums  [C*D]          1 MB  (zeroed by hist_kernel)
// No buffer is read before being fully written.

// 64 blocks x 256 threads; block b histograms rows [b*4096,(b+1)*4096).
// Also zeroes sums[] (grid-stride) since d_ws arrives poisoned 0xAA.
__global__ __launch_bounds__(256) void hist_kernel(
        const int* __restrict__ labels, int* __restrict__ hist,
        float4* __restrict__ sums4) {
    __shared__ int h[CPAD];
    int t = threadIdx.x;
    for (int i = t; i < CPAD; i += 256) h[i] = 0;
    // zero sums: C*D/4 = 64000 float4s over 64 blocks x 256 threads
    for (int i = blockIdx.x * 256 + t; i < C * D / 4; i += NB * 256)
        sums4[i] = float4{0.f, 0.f, 0.f, 0.f};
    __syncthreads();
    int base = blockIdx.x * ROWS_PER_B;
    for (int i = t; i < ROWS_PER_B; i += 256)
        atomicAdd(&h[labels[base + i]], 1);
    __syncthreads();
    int* out = hist + blockIdx.x * CPAD;
    for (int i = t; i < CPAD; i += 256) out[i] = h[i];
}

// 64 blocks x 256 threads. Each block redundantly computes the class scan
// (hist is 256 KB, L2-resident after first touch) + its own cursor base
// (prefix over earlier blocks) -- no serial single-CU kernel, no global
// atomics. Then scatters its 4096 rows via LDS cursors as packed
// (row<<10)|label into sorted position. Block 0 also writes counts[] for ema.
__global__ __launch_bounds__(256) void scatter_kernel(
        const int* __restrict__ labels,
        const int* __restrict__ hist,
        int* __restrict__ counts,
        int* __restrict__ S) {
    __shared__ int s[CPAD];    // scan array
    __shared__ int cu[CPAD];   // cursors
    int t = threadIdx.x;
    int myb = blockIdx.x;

    // totals (t, t+256, t+512, t+768) and prefix over blocks < myb
    int tot[4] = {0, 0, 0, 0};
    int pre[4] = {0, 0, 0, 0};
    for (int b = 0; b < NB; ++b) {
        #pragma unroll
        for (int c = 0; c < 4; ++c) {
            int v = hist[b * CPAD + c * 256 + t];
            tot[c] += v;
            if (b < myb) pre[c] += v;
        }
    }
    #pragma unroll
    for (int c = 0; c < 4; ++c) s[c * 256 + t] = tot[c];
    __syncthreads();
    // Hillis-Steele inclusive scan over 1024 entries, 256 threads x 4
    for (int off = 1; off < CPAD; off <<= 1) {
        int add[4];
        #pragma unroll
        for (int c = 0; c < 4; ++c) {
            int idx = c * 256 + t;
            add[c] = (idx >= off) ? s[idx - off] : 0;
        }
        __syncthreads();
        #pragma unroll
        for (int c = 0; c < 4; ++c) s[c * 256 + t] += add[c];
        __syncthreads();
    }
    #pragma unroll
    for (int c = 0; c < 4; ++c) {
        int idx = c * 256 + t;
        cu[idx] = s[idx] - tot[c] + pre[c];   // excl class scan + block prefix
        if (myb == 0) counts[idx] = tot[c];
    }
    __syncthreads();

    int base = myb * ROWS_PER_B;
    for (int i = t; i < ROWS_PER_B; i += 256) {
        int row = base + i;
        int lab = labels[row];
        int pos = atomicAdd(&cu[lab], 1);
        S[pos] = (row << 10) | lab;
    }
}

// 1024 blocks x 256 threads: each wave reduces 64 consecutive sorted slots;
// lane l covers dims [4l,4l+3]. 8 gathers in flight per wave; wave-uniform
// class-boundary flushes via f32 atomics (~2 per wave).
__global__ __launch_bounds__(256) void seg_reduce_kernel(
        const vfloat4* __restrict__ feat4,
        const int* __restrict__ S,
        float* __restrict__ sums) {
    int wave = threadIdx.x >> 6;
    int lane = threadIdx.x & 63;
    int base = (blockIdx.x * 4 + wave) * 64;   // this wave's 64 sorted slots
    int packed = S[base + lane];               // coalesced; slot i in lane i

    vfloat4 acc = (vfloat4)0.f;
    int cur = __shfl(packed, 0) & 1023;

    #pragma unroll 1
    for (int i = 0; i < 64; i += 8) {
        int pk[8];
        vfloat4 v[8];
        #pragma unroll
        for (int j = 0; j < 8; ++j) pk[j] = __shfl(packed, i + j);
        #pragma unroll
        for (int j = 0; j < 8; ++j)
            v[j] = __builtin_nontemporal_load(&feat4[(long)(pk[j] >> 10) * D4 + lane]);
        #pragma unroll
        for (int j = 0; j < 8; ++j) {
            int lab = pk[j] & 1023;
            if (lab != cur) {              // wave-uniform, rare
                float* dst = sums + cur * D + lane * 4;
                unsafeAtomicAdd(dst + 0, acc.x);
                unsafeAtomicAdd(dst + 1, acc.y);
                unsafeAtomicAdd(dst + 2, acc.z);
                unsafeAtomicAdd(dst + 3, acc.w);
                acc = (vfloat4)0.f;
                cur = lab;
            }
            acc += v[j];
        }
    }
    float* dst = sums + cur * D + lane * 4;
    unsafeAtomicAdd(dst + 0, acc.x);
    unsafeAtomicAdd(dst + 1, acc.y);
    unsafeAtomicAdd(dst + 2, acc.z);
    unsafeAtomicAdd(dst + 3, acc.w);
}

// EMA epilogue: one thread per float4 of the C x D output.
__global__ __launch_bounds__(256) void ema_kernel(
        const float4* __restrict__ cen4,
        const float* __restrict__ sums,
        const int* __restrict__ counts,
        float4* __restrict__ out4) {
    int idx = blockIdx.x * 256 + threadIdx.x;   // 0 .. C*64-1
    if (idx >= C * D4) return;
    int c = idx >> 6;
    int cnt = counts[c];
    float4 cen = cen4[idx];
    float4 o = cen;
    if (cnt > 0) {
        const float* sp = sums + c * D + (idx & 63) * 4;
        float s = ALPHA / (float)cnt;
        o.x = (1.0f - ALPHA) * cen.x + sp[0] * s;
        o.y = (1.0f - ALPHA) * cen.y + sp[1] * s;
        o.z = (1.0f - ALPHA) * cen.z + sp[2] * s;
        o.w = (1.0f - ALPHA) * cen.w + sp[3] * s;
    }
    out4[idx] = o;
}

extern "C" void kernel_launch(void* const* d_in, const int* in_sizes, int n_in,
                              void* d_out, int out_size, void* d_ws, size_t ws_size,
                              hipStream_t stream) {
    const vfloat4* feat4  = (const vfloat4*)d_in[0];
    const int*     labels = (const int*)d_in[1];
    const float4*  cen4   = (const float4*)d_in[2];
    float4*        out4   = (float4*)d_out;

    int*   hist   = (int*)d_ws;
    int*   counts = hist + NB * CPAD;
    int*   S      = counts + CPAD;
    float* sums   = (float*)(S + N);

    hist_kernel<<<NB, 256, 0, stream>>>(labels, hist, (float4*)sums);
    scatter_kernel<<<NB, 256, 0, stream>>>(labels, hist, counts, S);
    seg_reduce_kernel<<<N / 256, 256, 0, stream>>>(feat4, S, sums);
    ema_kernel<<<(C * D4 + 255) / 256, 256, 0, stream>>>(cen4, sums, counts, out4);
}